// Round 12
// baseline (644.585 us; speedup 1.0000x reference)
//
#include <hip/hip_runtime.h>

// ---------------------------------------------------------------------------
// LavaNetwork, bit-exact 4-plane i8 MFMA GEMM (mfma_i32_16x16x64_i8).
//   w ~ k*2^-31 (k = rint(w*2^31), residual <= 2^-32), 4 balanced base-256
//   digits -> exact i8 planes, exact i32 sums, exact i64 Horner + f64 bias.
// Round-21 structure (round-20 + fused layer-2 gemm_lif2):
//   - gemm_lif1: round-20 proven (8 GEMM waves + 1 LIF wave, 160 KB LDS,
//     whole-K weights resident, raw lgkmcnt pass barriers, act ring d2).
//   - NEW gemm_lif2 replaces gemm_i8<false> + lif_lds: block = (b, 16m) x
//     all 1024 t; whole K=2048 weight slab resident in LDS (128 KB,
//     barrier-free k-loop, no restaging); 4 GEMM waves (32t x 16m per
//     128-t pass) + 1 LIF wave (16 chains, register-preloaded groups)
//     writing spk2 f32 DIRECTLY (independent stores, no bpermute -- the
//     r8 failure mode was dependent shfl chains, absent here).
//     Deletes 32 MB cur2 write + 64 MB lif_lds round-trip + 1 launch.
//     Grid (32 b, 16 mb): same-b blocks share one XCD's L2 for spk8.
//   - expand_both kept (masks -> spk8 + spk1); preps unchanged.
//   - LIF recurrence identical arithmetic: u = 0.95*u + c; on spike u = c
//     next step (== 0.95*0 + c exactly), f64 state, f32 inputs.
// Fallback: round-3 proven f16 path if ws too small.
// ---------------------------------------------------------------------------

typedef int i32x4 __attribute__((ext_vector_type(4)));
typedef _Float16 f16x8 __attribute__((ext_vector_type(8)));
typedef _Float16 f16x4 __attribute__((ext_vector_type(4)));
typedef float f32x4 __attribute__((ext_vector_type(4)));

#define GLDS(g, l) __builtin_amdgcn_global_load_lds( \
    (const __attribute__((address_space(1))) void*)(g), \
    (__attribute__((address_space(3))) void*)(l), 16, 0, 0)

#define INV231 4.656612873077392578125e-10   // 2^-31

// ======================= prep =======================

// w (M,K) f32 -> wp [K/64][4][M][64] i8 digit planes; 16-B chunk c of row m
// stored at c ^ ((m>>1)&3)  (round-6/8-proven conflict-free for ds_read_b128).
__global__ __launch_bounds__(256) void prep_w8(const float* __restrict__ A,
                                               signed char* __restrict__ wp,
                                               int M, int K)
{
    long gt = (long)blockIdx.x * 256 + threadIdx.x;
    int kq4 = K >> 2;
    int m = (int)(gt / kq4), kq = (int)(gt % kq4);
    int k0 = kq * 4;
    int kt = k0 >> 6, kin = k0 & 63;
    int cw = ((kin >> 4) ^ (m >> 1)) & 3;
    float4 w = *(const float4*)&A[(long)m * K + k0];
    float wv[4] = {w.x, w.y, w.z, w.w};
    int pack[4] = {0, 0, 0, 0};
#pragma unroll
    for (int e = 0; e < 4; e++) {
        long k64 = (long)rint((double)wv[e] * 2147483648.0);  // * 2^31
#pragma unroll
        for (int j = 0; j < 3; j++) {
            long r = ((k64 + 128) & 255) - 128;   // balanced digit [-128,127]
            pack[j] |= ((int)r & 255) << (e * 8);
            k64 = (k64 - r) >> 8;
        }
        pack[3] |= ((int)k64 & 255) << (e * 8);
    }
#pragma unroll
    for (int p = 0; p < 4; p++)
        *(int*)&wp[(((long)kt * 4 + p) * M + m) * 64 + cw * 16 + (kin & 15)] = pack[p];
}

// x [b][512][1024] f32 -> x8t [b][8][1024][64] i8 (k-tile-major, plain layout
// for direct coalesced frag loads; no swizzle).
__global__ __launch_bounds__(256) void prep_x8(const float* __restrict__ x,
                                               unsigned char* __restrict__ xt)
{
    __shared__ float xs[64][68];
    const int b = blockIdx.z, i0 = blockIdx.y * 64, t0 = blockIdx.x * 64;
    const float* xb = x + ((long)b * 512 + i0) * 1024 + t0;
#pragma unroll
    for (int p = 0; p < 4; p++) {
        int f = threadIdx.x + p * 256;
        int i = f >> 4, t4 = (f & 15) * 4;
        *(float4*)&xs[i][t4] = *(const float4*)&xb[(long)i * 1024 + t4];
    }
    __syncthreads();
    int tt = threadIdx.x >> 2, c = threadIdx.x & 3;
    unsigned char bytes[16];
#pragma unroll
    for (int j = 0; j < 16; j++)
        bytes[j] = (unsigned char)xs[c * 16 + j][tt];
    *(uint4*)&xt[(((long)b * 8 + (i0 >> 6)) * 1024 + t0 + tt) * 64 + c * 16] =
        *(uint4*)bytes;
}

// ======================= fused layer-1 GEMM + LIF =======================
// Block = (64 m, b) x ALL 1024 t. 576 threads: waves 0-7 GEMM, wave 8 = LIF
// (64 lanes, chain for col m0+lane). GEMM wave w owns the quadrant
// (m-slice (w&3)*16, t-slice (w>>2)*32) of each 64t x 64m pass.
// LDS: Ws[8][4][64][64] = 128 KB + cs[2][64][64] f32 = 32 KB = 160 KB.
// 16 t-passes of 64; raw lgkmcnt-only barriers; act ring dist 2; setprio.
// Output: 1024-bit spike masks only.
__global__ __launch_bounds__(576, 1) void gemm_lif1(
    const signed char* __restrict__ wp,     // [8][4][2048][64] swizzled
    const unsigned char* __restrict__ act,  // [b][8][1024][64] plain
    const float* __restrict__ bias,         // (2048)
    unsigned* __restrict__ mask_ws)         // [b][32][2048]
{
    __shared__ signed char Ws[8][4][64][64];   // 128 KB
    __shared__ float cs[2][64][64];            // 32 KB

    const int m0 = blockIdx.x * 64, b = blockIdx.y;
    const int tid = threadIdx.x, lane = tid & 63, wave = tid >> 6;
    const int lm = lane & 15, lq = lane >> 4;
    const int fro = ((lq ^ (lm >> 1)) & 3) * 16;   // swizzled LDS read offset
    const int mw = wave & 3;            // m-slice (GEMM waves)
    const int tw2 = wave >> 2;          // t-slice 0/1 (GEMM waves)
    const unsigned char* ab = act + (long)b * 8 * 1024 * 64;

    i32x4 areg[4][2];   // 4-slot ring x 2 t-frags, prefetch distance 2
    double bv = 0.0;

    if (wave < 8) {
        const int gl_row = lane >> 2, gl_col = (lane & 3) * 16;
#pragma unroll
        for (int j = 0; j < 4; ++j) {
            const int r = wave + 8 * j;          // slab id 0..31
            const int kt = r >> 2, pl = r & 3;
            const signed char* g = wp + ((long)r * 2048 + m0 + gl_row) * 64 + gl_col;
#pragma unroll
            for (int q = 0; q < 4; ++q)
                GLDS(g + q * 16 * 64, &Ws[kt][pl][q * 16][0]);
        }
        bv = (double)bias[m0 + mw * 16 + lm];
#pragma unroll
        for (int f = 0; f < 2; f++)
            areg[0][f] = *(const i32x4*)
                &ab[((long)(tw2 * 32 + f * 16 + lm)) * 64 + lq * 16];          // kt 0
#pragma unroll
        for (int f = 0; f < 2; f++)
            areg[1][f] = *(const i32x4*)
                &ab[((long)1 * 1024 + tw2 * 32 + f * 16 + lm) * 64 + lq * 16]; // kt 1
    }
    __syncthreads();   // full drain: GLDS weights must be resident

    double u = 0.0;
    bool sprev = false;

    for (int p = 0; p < 17; ++p) {
        if (wave < 8 && p < 16) {
            i32x4 acc[4][2];   // [plane][t-frag]
#pragma unroll
            for (int pp = 0; pp < 4; pp++)
#pragma unroll
                for (int f = 0; f < 2; f++) acc[pp][f] = (i32x4)0;

#pragma unroll
            for (int kk = 0; kk < 8; ++kk) {
                {
                    int vn = p * 8 + kk + 2;
                    if (vn > 127) vn = 127;      // redundant reload, same addr
                    const int pn = vn >> 3, kn = vn & 7;
                    const long tt = (long)pn * 64 + tw2 * 32 + lm;
#pragma unroll
                    for (int f = 0; f < 2; f++)
                        areg[(kk + 2) & 3][f] = *(const i32x4*)
                            &ab[((long)kn * 1024 + tt + f * 16) * 64 + lq * 16];
                }
                __builtin_amdgcn_s_setprio(1);
#pragma unroll
                for (int pl = 0; pl < 4; pl++) {
                    i32x4 w0 = *(const i32x4*)&Ws[kk][pl][mw * 16 + lm][fro];
#pragma unroll
                    for (int f = 0; f < 2; f++)
                        acc[pl][f] = __builtin_amdgcn_mfma_i32_16x16x64_i8(
                            areg[kk & 3][f], w0, acc[pl][f], 0, 0, 0);
                }
                __builtin_amdgcn_s_setprio(0);
            }
#pragma unroll
            for (int tf = 0; tf < 2; tf++)
#pragma unroll
                for (int r = 0; r < 4; r++) {
                    long T = acc[3][tf][r];
                    T = T * 256 + acc[2][tf][r];
                    T = T * 256 + acc[1][tf][r];
                    T = T * 256 + acc[0][tf][r];
                    cs[p & 1][tw2 * 32 + tf * 16 + lq * 4 + r][mw * 16 + lm] =
                        (float)((double)T * INV231 + bv);
                }
        }
        if (wave == 8 && p >= 1) {
            const int pq = p - 1, buf = pq & 1;
            float cvA[32], cvB[32];
#pragma unroll
            for (int j = 0; j < 32; ++j) cvA[j] = cs[buf][j][lane];
#pragma unroll
            for (int j = 0; j < 32; ++j) cvB[j] = cs[buf][32 + j][lane];
            {   // t-word pq*2
                unsigned mword = 0;
#pragma unroll
                for (int j = 0; j < 32; ++j) {
                    double c = (double)cvA[j];
                    double a = 0.95 * u + c;
                    u = sprev ? c : a;
                    bool s = (u >= 1.0);
                    mword |= (s ? 1u : 0u) << j;
                    sprev = s;
                }
                mask_ws[((long)b * 32 + pq * 2 + 0) * 2048 + m0 + lane] = mword;
            }
            {   // t-word pq*2+1
                unsigned mword = 0;
#pragma unroll
                for (int j = 0; j < 32; ++j) {
                    double c = (double)cvB[j];
                    double a = 0.95 * u + c;
                    u = sprev ? c : a;
                    bool s = (u >= 1.0);
                    mword |= (s ? 1u : 0u) << j;
                    sprev = s;
                }
                mask_ws[((long)b * 32 + pq * 2 + 1) * 2048 + m0 + lane] = mword;
            }
        }
        asm volatile("s_waitcnt lgkmcnt(0)" ::: "memory");
        __builtin_amdgcn_s_barrier();
        __builtin_amdgcn_sched_barrier(0);
    }
}

// ======================= combined mask expander =======================
// masks [b][32][2048] -> spk8 i8 [b][32 kt][1024 t][64 m]  AND
//                        spk1 f32 [b][2048 m][1024 t]
__global__ __launch_bounds__(256) void expand_both(
    const unsigned* __restrict__ mask_ws,
    unsigned char* __restrict__ spk8,
    float* __restrict__ spk1)
{
    __shared__ unsigned msk[64][33];
    const int b = blockIdx.x, kt = blockIdx.y;
    const int tid = threadIdx.x;
#pragma unroll
    for (int i = 0; i < 8; ++i) {
        int idx = tid + i * 256;            // 0..2047
        int tw = idx >> 6, m = idx & 63;
        msk[m][tw] = mask_ws[((long)b * 32 + tw) * 2048 + kt * 64 + m];
    }
    __syncthreads();
    unsigned char* dst = spk8 + ((long)b * 32 + kt) * 1024 * 64;
#pragma unroll
    for (int i = 0; i < 16; ++i) {
        int off = tid + i * 256;            // 16-B chunk index 0..4095
        int t = off >> 2, mq = off & 3;
        int tw = t >> 5, sh = t & 31;
        unsigned w0 = 0, w1 = 0, w2 = 0, w3 = 0;
#pragma unroll
        for (int j = 0; j < 4; ++j) {
            w0 |= ((msk[mq * 16 + j][tw] >> sh) & 1u) << (8 * j);
            w1 |= ((msk[mq * 16 + 4 + j][tw] >> sh) & 1u) << (8 * j);
            w2 |= ((msk[mq * 16 + 8 + j][tw] >> sh) & 1u) << (8 * j);
            w3 |= ((msk[mq * 16 + 12 + j][tw] >> sh) & 1u) << (8 * j);
        }
        *(uint4*)&dst[(long)off * 16] = (uint4){w0, w1, w2, w3};
    }
    const int rr = tid >> 5, l5 = tid & 31;
    const int sh1 = (l5 & 7) * 4;
#pragma unroll
    for (int rep = 0; rep < 8; ++rep) {
        const int row = rr + rep * 8;       // 0..63
        float* d1 = spk1 + ((long)b * 2048 + kt * 64 + row) * 1024;
#pragma unroll
        for (int j = 0; j < 8; j++) {
            const int t = l5 * 4 + j * 128;
            const unsigned w = msk[row][(l5 >> 3) + j * 4];
            float4 o;
            o.x = ((w >> sh1) & 1u) ? 1.f : 0.f;
            o.y = ((w >> (sh1 + 1)) & 1u) ? 1.f : 0.f;
            o.z = ((w >> (sh1 + 2)) & 1u) ? 1.f : 0.f;
            o.w = ((w >> (sh1 + 3)) & 1u) ? 1.f : 0.f;
            *(float4*)&d1[t] = o;
        }
    }
}

// ======================= fused layer-2 GEMM + LIF =======================
// Block = (b, 16 m) x ALL 1024 t. 320 threads: waves 0-3 GEMM (32t x 16m
// each per 128-t pass), wave 4 = LIF2 (lanes 0-15, chain for row m0+lane,
// writes spk2 f32 directly).
// LDS: Ws[32][4][16][64] = 128 KB (whole K=2048 slab for 16 m rows, staged
// once -> k-loop is barrier-free, zero restaging) + cs[2][128][17] = 17.4 KB.
// 8 t-passes of 128; raw lgkmcnt-only pass barriers; act ring dist 2.
// Grid dim3(32 b, 16 mb): same-b blocks (sharing the 2 MB spk8 slab) have
// dispatch-id stride 32 == 0 mod 8 -> same XCD L2.
__global__ __launch_bounds__(320, 1) void gemm_lif2(
    const signed char* __restrict__ wp,     // [32][4][256][64] swizzled
    const unsigned char* __restrict__ act,  // [b][32][1024][64] spk8
    const float* __restrict__ bias,         // (256)
    float* __restrict__ spk2)               // [b][256][1024] f32 spikes
{
    __shared__ signed char Ws[32][4][16][64];  // 128 KB
    __shared__ float cs[2][128][17];           // 17.4 KB

    const int b = blockIdx.x, m0 = blockIdx.y * 16;
    const int tid = threadIdx.x, lane = tid & 63, wave = tid >> 6;
    const int lm = lane & 15, lq = lane >> 4;
    const int fro = ((lq ^ (lm >> 1)) & 3) * 16;   // swizzled LDS read offset
    const unsigned char* ab = act + (long)b * 32 * 1024 * 64;

    i32x4 areg[4][2];   // 4-slot ring x 2 t-frags, prefetch distance 2
    double bvr[4] = {0.0, 0.0, 0.0, 0.0};

    if (wave < 4) {
        // stage whole weight slab: 128 slabs (kt,pl) of [16][64]=1KB each,
        // exactly one GLDS (64 lanes x 16 B) per slab; 32 slabs/wave
        const int gl_row = lane >> 2, gl_col = (lane & 3) * 16;
#pragma unroll
        for (int j = 0; j < 32; ++j) {
            const int r = wave + 4 * j;          // slab id 0..127
            const int kt = r >> 2, pl = r & 3;
            const signed char* g =
                wp + (((long)kt * 4 + pl) * 256 + m0 + gl_row) * 64 + gl_col;
            GLDS(g, &Ws[kt][pl][0][0]);
        }
#pragma unroll
        for (int r = 0; r < 4; ++r)
            bvr[r] = (double)bias[m0 + lq * 4 + r];
        // act ring prologue: kt 0 (slot 0), kt 1 (slot 1), pass-0 t-slice
        {
            const long wt0 = wave * 32 + lm;
#pragma unroll
            for (int f = 0; f < 2; f++)
                areg[0][f] = *(const i32x4*)&ab[(wt0 + f * 16) * 64 + lq * 16];
#pragma unroll
            for (int f = 0; f < 2; f++)
                areg[1][f] = *(const i32x4*)
                    &ab[((long)1 * 1024 + wt0 + f * 16) * 64 + lq * 16];
        }
    }
    __syncthreads();   // full drain: GLDS weights must be resident

    // LIF2 state (wave 4, lanes 0-15: chain for row m0+lane)
    double u = 0.0;
    bool sprev = false;
    float* sp2 = spk2 + ((long)b * 256 + m0 + (lane & 15)) * 1024;

    for (int p = 0; p < 9; ++p) {
        if (wave < 4 && p < 8) {
            i32x4 acc[4][2];   // [plane][t-frag]
#pragma unroll
            for (int pp = 0; pp < 4; pp++)
#pragma unroll
                for (int f = 0; f < 2; f++) acc[pp][f] = (i32x4)0;

            // barrier-free k-loop over all 32 k-tiles (weights resident)
#pragma unroll 4
            for (int kt = 0; kt < 32; ++kt) {
                {
                    int vn = p * 32 + kt + 2;          // virtual act iter
                    if (vn > 255) vn = 255;            // redundant reload
                    const int pn = vn >> 5, kn = vn & 31;
                    const long tt = (long)pn * 128 + wave * 32 + lm;
#pragma unroll
                    for (int f = 0; f < 2; f++)
                        areg[(kt + 2) & 3][f] = *(const i32x4*)
                            &ab[((long)kn * 1024 + tt + f * 16) * 64 + lq * 16];
                }
                __builtin_amdgcn_s_setprio(1);
#pragma unroll
                for (int pl = 0; pl < 4; pl++) {
                    i32x4 w0 = *(const i32x4*)&Ws[kt][pl][lm][fro];
#pragma unroll
                    for (int f = 0; f < 2; f++)
                        acc[pl][f] = __builtin_amdgcn_mfma_i32_16x16x64_i8(
                            w0, areg[kt & 3][f], acc[pl][f], 0, 0, 0);
                }
                __builtin_amdgcn_s_setprio(0);
            }
            // Horner -> exact f32 current -> cs[p&1][t][m]
            // D[m][t]: row m = lq*4+r, col t = (wave*32 + tf*16 + lm)
#pragma unroll
            for (int tf = 0; tf < 2; tf++)
#pragma unroll
                for (int r = 0; r < 4; r++) {
                    long T = acc[3][tf][r];
                    T = T * 256 + acc[2][tf][r];
                    T = T * 256 + acc[1][tf][r];
                    T = T * 256 + acc[0][tf][r];
                    cs[p & 1][wave * 32 + tf * 16 + lm][lq * 4 + r] =
                        (float)((double)T * INV231 + bvr[r]);
                }
        }
        if (wave == 4 && p >= 1 && lane < 16) {
            const int pq = p - 1, buf = pq & 1;
            float* sp = sp2 + pq * 128;
            // 4 groups of 32 steps, register-preload pipelined (r5 proven),
            // spikes stored f32 directly (independent stores, no waits)
            float cvA[32], cvB[32];
#pragma unroll
            for (int j = 0; j < 32; ++j) cvA[j] = cs[buf][j][lane];
#pragma unroll
            for (int j = 0; j < 32; ++j) cvB[j] = cs[buf][32 + j][lane];
            {   // g = 0 (chain cvA)
#pragma unroll
                for (int j = 0; j < 32; ++j) {
                    double c = (double)cvA[j];
                    double a = 0.95 * u + c;
                    u = sprev ? c : a;
                    bool s = (u >= 1.0);
                    sp[j] = s ? 1.f : 0.f;
                    sprev = s;
                }
            }
#pragma unroll
            for (int j = 0; j < 32; ++j) cvA[j] = cs[buf][64 + j][lane];
            {   // g = 1 (chain cvB)
#pragma unroll
                for (int j = 0; j < 32; ++j) {
                    double c = (double)cvB[j];
                    double a = 0.95 * u + c;
                    u = sprev ? c : a;
                    bool s = (u >= 1.0);
                    sp[32 + j] = s ? 1.f : 0.f;
                    sprev = s;
                }
            }
#pragma unroll
            for (int j = 0; j < 32; ++j) cvB[j] = cs[buf][96 + j][lane];
            {   // g = 2 (chain cvA)
#pragma unroll
                for (int j = 0; j < 32; ++j) {
                    double c = (double)cvA[j];
                    double a = 0.95 * u + c;
                    u = sprev ? c : a;
                    bool s = (u >= 1.0);
                    sp[64 + j] = s ? 1.f : 0.f;
                    sprev = s;
                }
            }
            {   // g = 3 (chain cvB)
#pragma unroll
                for (int j = 0; j < 32; ++j) {
                    double c = (double)cvB[j];
                    double a = 0.95 * u + c;
                    u = sprev ? c : a;
                    bool s = (u >= 1.0);
                    sp[96 + j] = s ? 1.f : 0.f;
                    sprev = s;
                }
            }
        }
        // raw pass barrier: only LDS (cs) crosses it -> lgkmcnt(0) suffices;
        // in-flight GLOBAL act loads / spike stores intentionally survive.
        asm volatile("s_waitcnt lgkmcnt(0)" ::: "memory");
        __builtin_amdgcn_s_barrier();
        __builtin_amdgcn_sched_barrier(0);
    }
}

// ======================= fallback (round 3, proven) =======================

__device__ inline void split3(float w, _Float16& q0, _Float16& q1, _Float16& q2) {
    float p0 = rintf(w * 4096.f) * 2.44140625e-4f;
    float r1 = w - p0;
    float p1s = rintf(r1 * 8388608.f) * 2.44140625e-4f;
    float r2 = r1 - p1s * 4.8828125e-4f;
    float p2s = rintf(r2 * 1.7179869184e10f) * 1.220703125e-4f;
    q0 = (_Float16)p0; q1 = (_Float16)p1s; q2 = (_Float16)p2s;
}

__global__ __launch_bounds__(256) void gemm_f16x3_kernel(
    const float* __restrict__ A, const float* __restrict__ Bmat,
    const float* __restrict__ bias, float* __restrict__ C,
    int M, int N, int K, long sB, long sC)
{
    __shared__ _Float16 As[3][128][40];
    __shared__ _Float16 Bsh[128][40];
    const int batch = blockIdx.z;
    const float* Bp = Bmat + (long)batch * sB;
    float* Cp = C + (long)batch * sC;
    const int m0 = blockIdx.y * 128, n0 = blockIdx.x * 128;
    const int tid = threadIdx.x, lane = tid & 63, wave = tid >> 6;
    const int wrow = (wave >> 1) * 64, wcol = (wave & 1) * 64;
    const int lm = lane & 15, lq = lane >> 4;
    const int a_mo = tid >> 3, a_kc = (tid & 7) * 4;
    const int b_kq = tid >> 5, b_nq = tid & 31;

    f32x4 acc[3][4][4];
#pragma unroll
    for (int p = 0; p < 3; p++)
#pragma unroll
        for (int i = 0; i < 4; i++)
#pragma unroll
            for (int j = 0; j < 4; j++) acc[p][i][j] = (f32x4)0.f;

    for (int k0 = 0; k0 < K; k0 += 32) {
#pragma unroll
        for (int i = 0; i < 4; i++) {
            const int m = i * 32 + a_mo;
            float4 w = *(const float4*)&A[(long)(m0 + m) * K + k0 + a_kc];
            _Float16 a0[4], a1[4], a2[4];
            split3(w.x, a0[0], a1[0], a2[0]);
            split3(w.y, a0[1], a1[1], a2[1]);
            split3(w.z, a0[2], a1[2], a2[2]);
            split3(w.w, a0[3], a1[3], a2[3]);
            *(f16x4*)&As[0][m][a_kc] = (f16x4){a0[0], a0[1], a0[2], a0[3]};
            *(f16x4*)&As[1][m][a_kc] = (f16x4){a1[0], a1[1], a1[2], a1[3]};
            *(f16x4*)&As[2][m][a_kc] = (f16x4){a2[0], a2[1], a2[2], a2[3]};
        }
        {
            float4 r0 = *(const float4*)&Bp[(long)(k0 + b_kq * 4 + 0) * N + n0 + b_nq * 4];
            float4 r1 = *(const float4*)&Bp[(long)(k0 + b_kq * 4 + 1) * N + n0 + b_nq * 4];
            float4 r2 = *(const float4*)&Bp[(long)(k0 + b_kq * 4 + 2) * N + n0 + b_nq * 4];
            float4 r3 = *(const float4*)&Bp[(long)(k0 + b_kq * 4 + 3) * N + n0 + b_nq * 4];
            *(f16x4*)&Bsh[b_nq * 4 + 0][b_kq * 4] =
                (f16x4){(_Float16)r0.x, (_Float16)r1.x, (_Float16)r2.x, (_Float16)r3.x};
            *(f16x4*)&Bsh[b_nq * 4 + 1][b_kq * 4] =
                (f16x4){(_Float16)r0.y, (_Float16)r1.y, (_Float16)r2.y, (_Float16)r3.y};
            *(f16x4*)&Bsh[b_nq * 4 + 2][b_kq * 4] =
                (f16x4){(_Float16)r0.z, (_Float16)r1.z, (_Float16)r2.z, (_Float16)r3.z};
            *(f16x4*)&Bsh[b_nq * 4 + 3][b_kq * 4] =
                (f16x4){(_Float16)r0.w, (_Float16)r1.w, (_Float16)r2.w, (_Float16)r3.w};
        }
        __syncthreads();
        f16x8 bf[4];
#pragma unroll
        for (int j = 0; j < 4; j++)
            bf[j] = *(const f16x8*)&Bsh[wcol + j * 16 + lm][lq * 8];
#pragma unroll
        for (int p = 0; p < 3; p++) {
            f16x8 af[4];
#pragma unroll
            for (int i = 0; i < 4; i++)
                af[i] = *(const f16x8*)&As[p][wrow + i * 16 + lm][lq * 8];
#pragma unroll
            for (int i = 0; i < 4; i++)
#pragma unroll
                for (int j = 0; j < 4; j++)
                    acc[p][i][j] = __builtin_amdgcn_mfma_f32_16x16x32_f16(
                        af[i], bf[j], acc[p][i][j], 0, 0, 0);
        }
        __syncthreads();
    }
#pragma unroll
    for (int i = 0; i < 4; i++)
#pragma unroll
        for (int r = 0; r < 4; r++) {
            const int row = m0 + wrow + i * 16 + lq * 4 + r;
            const double bv = (double)bias[row];
#pragma unroll
            for (int j = 0; j < 4; j++) {
                double s = (double)acc[0][i][j][r]
                         + (double)acc[1][i][j][r] * 4.8828125e-4
                         + (double)acc[2][i][j][r] * 4.76837158203125e-7 + bv;
                Cp[(long)row * N + n0 + wcol + j * 16 + lm] = (float)s;
            }
        }
}

__global__ __launch_bounds__(256) void lif_rows(float* __restrict__ data,
                                                long nrows, int T)
{
    long r = (long)blockIdx.x * blockDim.x + threadIdx.x;
    if (r >= nrows) return;
    float* p = data + r * (long)T;
    double v = 0.0;
    for (int t = 0; t < T; t += 4) {
        float4 c = *(float4*)(p + t);
        float4 s;
        v = 0.95 * v + (double)c.x; s.x = (v >= 1.0) ? 1.f : 0.f; if (v >= 1.0) v = 0.0;
        v = 0.95 * v + (double)c.y; s.y = (v >= 1.0) ? 1.f : 0.f; if (v >= 1.0) v = 0.0;
        v = 0.95 * v + (double)c.z; s.z = (v >= 1.0) ? 1.f : 0.f; if (v >= 1.0) v = 0.0;
        v = 0.95 * v + (double)c.w; s.w = (v >= 1.0) ? 1.f : 0.f; if (v >= 1.0) v = 0.0;
        *(float4*)(p + t) = s;
    }
}

// ======================= launch =======================

extern "C" void kernel_launch(void* const* d_in, const int* in_sizes, int n_in,
                              void* d_out, int out_size, void* d_ws, size_t ws_size,
                              hipStream_t stream)
{
    const float* x  = (const float*)d_in[0];  // (32, 512, 1024)
    const float* w1 = (const float*)d_in[1];  // (2048, 512)
    const float* b1 = (const float*)d_in[2];  // (2048)
    const float* w2 = (const float*)d_in[3];  // (256, 2048)
    const float* b2 = (const float*)d_in[4];  // (256)

    float* out  = (float*)d_out;
    float* spk1 = out;                              // (32, 2048, 1024)
    float* spk2 = out + (long)32 * 2048 * 1024;     // (32, 256, 1024)

    const size_t WP1 = 4194304;        // [8][4][2048][64] i8
    const size_t WP2 = 2097152;        // [32][4][256][64] i8
    const size_t X8T = 16777216;       // [32][8][1024][64] i8
    const size_t SPK = 67108864;       // [32][32][1024][64] i8
    const size_t MSK = 8388608;        // [32][32][2048] u32
    const size_t NEED = WP1 + WP2 + X8T + SPK + MSK;

    if (ws_size >= NEED) {
        char* ws = (char*)d_ws;
        signed char* wp1 = (signed char*)ws;
        signed char* wp2 = (signed char*)(ws + WP1);
        unsigned char* x8t = (unsigned char*)(ws + WP1 + WP2);
        unsigned char* spk8 = (unsigned char*)(ws + WP1 + WP2 + X8T);
        unsigned* mask_ws = (unsigned*)(ws + WP1 + WP2 + X8T + SPK);

        prep_w8<<<1024, 256, 0, stream>>>(w1, wp1, 2048, 512);
        prep_w8<<<512, 256, 0, stream>>>(w2, wp2, 256, 2048);
        prep_x8<<<dim3(16, 8, 32), 256, 0, stream>>>(x, x8t);

        // layer 1: fused GEMM+LIF -> masks only; 8 GEMM waves + 1 LIF wave
        gemm_lif1<<<dim3(32, 32), 576, 0, stream>>>(wp1, x8t, b1, mask_ws);

        // combined expansion: masks -> spk8 i8 + spk1 f32 (one kernel)
        expand_both<<<dim3(32, 32), 256, 0, stream>>>(mask_ws, spk8, spk1);

        // layer 2: fused GEMM+LIF -> spk2 f32 directly (whole-K resident)
        gemm_lif2<<<dim3(32, 16), 320, 0, stream>>>(wp2, spk8, b2, spk2);
    } else {
        gemm_f16x3_kernel<<<dim3(8, 16, 32), 256, 0, stream>>>(
            w1, x, b1, spk1, 2048, 1024, 512, (long)512 * 1024, (long)2048 * 1024);
        lif_rows<<<(65536 + 255) / 256, 256, 0, stream>>>(spk1, 65536, 1024);
        gemm_f16x3_kernel<<<dim3(8, 2, 32), 256, 0, stream>>>(
            w2, spk1, b2, spk2, 256, 1024, 2048, (long)2048 * 1024, (long)256 * 1024);
        lif_rows<<<(8192 + 255) / 256, 256, 0, stream>>>(spk2, 8192, 1024);
    }
}

// Round 13
// 630.154 us; speedup vs baseline: 1.0229x; 1.0229x over previous
//
#include <hip/hip_runtime.h>

// ---------------------------------------------------------------------------
// LavaNetwork, bit-exact 4-plane i8 MFMA GEMM (mfma_i32_16x16x64_i8).
//   w ~ k*2^-31 (k = rint(w*2^31), residual <= 2^-32), 4 balanced base-256
//   digits -> exact i8 planes, exact i32 sums, exact i64 Horner + f64 bias.
// Round-22 structure (round-21 + 8-wave split in gemm_lif2 + merged preps):
//   - gemm_lif1: round-20 proven (8 GEMM waves + 1 LIF wave, 160 KB LDS,
//     whole-K weights resident, raw lgkmcnt pass barriers, act ring d2).
//   - gemm_lif2: now 576 threads = 8 GEMM waves (16t x 16m each per 128-t
//     pass, 2+ waves/SIMD fill each other's bubbles -- the r11-proven
//     lever; r12's 4-wave version was 1 wave/SIMD and lost to the
//     unfused pair) + 1 LIF wave (16 chains) writing spk2 f32 directly.
//     Whole K=2048 weight slab resident (128 KB), barrier-free k-loop.
//   - prep_w8_both: single dispatch covers both weight preps (one launch
//     less; per-block body identical to proven prep_w8).
//   - expand_both kept (masks -> spk8 + spk1); prep_x8 unchanged.
//   - LIF recurrence identical arithmetic: u = 0.95*u + c; on spike u = c
//     next step (== 0.95*0 + c exactly), f64 state, f32 inputs.
// Fallback: round-3 proven f16 path if ws too small.
// ---------------------------------------------------------------------------

typedef int i32x4 __attribute__((ext_vector_type(4)));
typedef _Float16 f16x8 __attribute__((ext_vector_type(8)));
typedef _Float16 f16x4 __attribute__((ext_vector_type(4)));
typedef float f32x4 __attribute__((ext_vector_type(4)));

#define GLDS(g, l) __builtin_amdgcn_global_load_lds( \
    (const __attribute__((address_space(1))) void*)(g), \
    (__attribute__((address_space(3))) void*)(l), 16, 0, 0)

#define INV231 4.656612873077392578125e-10   // 2^-31

// ======================= prep =======================

// w (M,K) f32 -> wp [K/64][4][M][64] i8 digit planes; 16-B chunk c of row m
// stored at c ^ ((m>>1)&3)  (round-6/8-proven conflict-free for ds_read_b128).
__device__ __forceinline__ void prep_w8_body(const float* __restrict__ A,
                                             signed char* __restrict__ wp,
                                             int M, int K, int bid, int tid)
{
    long gt = (long)bid * 256 + tid;
    int kq4 = K >> 2;
    int m = (int)(gt / kq4), kq = (int)(gt % kq4);
    int k0 = kq * 4;
    int kt = k0 >> 6, kin = k0 & 63;
    int cw = ((kin >> 4) ^ (m >> 1)) & 3;
    float4 w = *(const float4*)&A[(long)m * K + k0];
    float wv[4] = {w.x, w.y, w.z, w.w};
    int pack[4] = {0, 0, 0, 0};
#pragma unroll
    for (int e = 0; e < 4; e++) {
        long k64 = (long)rint((double)wv[e] * 2147483648.0);  // * 2^31
#pragma unroll
        for (int j = 0; j < 3; j++) {
            long r = ((k64 + 128) & 255) - 128;   // balanced digit [-128,127]
            pack[j] |= ((int)r & 255) << (e * 8);
            k64 = (k64 - r) >> 8;
        }
        pack[3] |= ((int)k64 & 255) << (e * 8);
    }
#pragma unroll
    for (int p = 0; p < 4; p++)
        *(int*)&wp[(((long)kt * 4 + p) * M + m) * 64 + cw * 16 + (kin & 15)] = pack[p];
}

// blocks 0..1023: w1 (2048x512) -> wp1; blocks 1024..1535: w2 (256x2048) -> wp2
__global__ __launch_bounds__(256) void prep_w8_both(
    const float* __restrict__ w1, signed char* __restrict__ wp1,
    const float* __restrict__ w2, signed char* __restrict__ wp2)
{
    if (blockIdx.x < 1024)
        prep_w8_body(w1, wp1, 2048, 512, blockIdx.x, threadIdx.x);
    else
        prep_w8_body(w2, wp2, 256, 2048, blockIdx.x - 1024, threadIdx.x);
}

// x [b][512][1024] f32 -> x8t [b][8][1024][64] i8 (k-tile-major, plain layout
// for direct coalesced frag loads; no swizzle).
__global__ __launch_bounds__(256) void prep_x8(const float* __restrict__ x,
                                               unsigned char* __restrict__ xt)
{
    __shared__ float xs[64][68];
    const int b = blockIdx.z, i0 = blockIdx.y * 64, t0 = blockIdx.x * 64;
    const float* xb = x + ((long)b * 512 + i0) * 1024 + t0;
#pragma unroll
    for (int p = 0; p < 4; p++) {
        int f = threadIdx.x + p * 256;
        int i = f >> 4, t4 = (f & 15) * 4;
        *(float4*)&xs[i][t4] = *(const float4*)&xb[(long)i * 1024 + t4];
    }
    __syncthreads();
    int tt = threadIdx.x >> 2, c = threadIdx.x & 3;
    unsigned char bytes[16];
#pragma unroll
    for (int j = 0; j < 16; j++)
        bytes[j] = (unsigned char)xs[c * 16 + j][tt];
    *(uint4*)&xt[(((long)b * 8 + (i0 >> 6)) * 1024 + t0 + tt) * 64 + c * 16] =
        *(uint4*)bytes;
}

// ======================= fused layer-1 GEMM + LIF =======================
// Block = (64 m, b) x ALL 1024 t. 576 threads: waves 0-7 GEMM, wave 8 = LIF
// (64 lanes, chain for col m0+lane). GEMM wave w owns the quadrant
// (m-slice (w&3)*16, t-slice (w>>2)*32) of each 64t x 64m pass.
// LDS: Ws[8][4][64][64] = 128 KB + cs[2][64][64] f32 = 32 KB = 160 KB.
// 16 t-passes of 64; raw lgkmcnt-only barriers; act ring dist 2; setprio.
// Output: 1024-bit spike masks only.
__global__ __launch_bounds__(576, 1) void gemm_lif1(
    const signed char* __restrict__ wp,     // [8][4][2048][64] swizzled
    const unsigned char* __restrict__ act,  // [b][8][1024][64] plain
    const float* __restrict__ bias,         // (2048)
    unsigned* __restrict__ mask_ws)         // [b][32][2048]
{
    __shared__ signed char Ws[8][4][64][64];   // 128 KB
    __shared__ float cs[2][64][64];            // 32 KB

    const int m0 = blockIdx.x * 64, b = blockIdx.y;
    const int tid = threadIdx.x, lane = tid & 63, wave = tid >> 6;
    const int lm = lane & 15, lq = lane >> 4;
    const int fro = ((lq ^ (lm >> 1)) & 3) * 16;   // swizzled LDS read offset
    const int mw = wave & 3;            // m-slice (GEMM waves)
    const int tw2 = wave >> 2;          // t-slice 0/1 (GEMM waves)
    const unsigned char* ab = act + (long)b * 8 * 1024 * 64;

    i32x4 areg[4][2];   // 4-slot ring x 2 t-frags, prefetch distance 2
    double bv = 0.0;

    if (wave < 8) {
        const int gl_row = lane >> 2, gl_col = (lane & 3) * 16;
#pragma unroll
        for (int j = 0; j < 4; ++j) {
            const int r = wave + 8 * j;          // slab id 0..31
            const int kt = r >> 2, pl = r & 3;
            const signed char* g = wp + ((long)r * 2048 + m0 + gl_row) * 64 + gl_col;
#pragma unroll
            for (int q = 0; q < 4; ++q)
                GLDS(g + q * 16 * 64, &Ws[kt][pl][q * 16][0]);
        }
        bv = (double)bias[m0 + mw * 16 + lm];
#pragma unroll
        for (int f = 0; f < 2; f++)
            areg[0][f] = *(const i32x4*)
                &ab[((long)(tw2 * 32 + f * 16 + lm)) * 64 + lq * 16];          // kt 0
#pragma unroll
        for (int f = 0; f < 2; f++)
            areg[1][f] = *(const i32x4*)
                &ab[((long)1 * 1024 + tw2 * 32 + f * 16 + lm) * 64 + lq * 16]; // kt 1
    }
    __syncthreads();   // full drain: GLDS weights must be resident

    double u = 0.0;
    bool sprev = false;

    for (int p = 0; p < 17; ++p) {
        if (wave < 8 && p < 16) {
            i32x4 acc[4][2];   // [plane][t-frag]
#pragma unroll
            for (int pp = 0; pp < 4; pp++)
#pragma unroll
                for (int f = 0; f < 2; f++) acc[pp][f] = (i32x4)0;

#pragma unroll
            for (int kk = 0; kk < 8; ++kk) {
                {
                    int vn = p * 8 + kk + 2;
                    if (vn > 127) vn = 127;      // redundant reload, same addr
                    const int pn = vn >> 3, kn = vn & 7;
                    const long tt = (long)pn * 64 + tw2 * 32 + lm;
#pragma unroll
                    for (int f = 0; f < 2; f++)
                        areg[(kk + 2) & 3][f] = *(const i32x4*)
                            &ab[((long)kn * 1024 + tt + f * 16) * 64 + lq * 16];
                }
                __builtin_amdgcn_s_setprio(1);
#pragma unroll
                for (int pl = 0; pl < 4; pl++) {
                    i32x4 w0 = *(const i32x4*)&Ws[kk][pl][mw * 16 + lm][fro];
#pragma unroll
                    for (int f = 0; f < 2; f++)
                        acc[pl][f] = __builtin_amdgcn_mfma_i32_16x16x64_i8(
                            areg[kk & 3][f], w0, acc[pl][f], 0, 0, 0);
                }
                __builtin_amdgcn_s_setprio(0);
            }
#pragma unroll
            for (int tf = 0; tf < 2; tf++)
#pragma unroll
                for (int r = 0; r < 4; r++) {
                    long T = acc[3][tf][r];
                    T = T * 256 + acc[2][tf][r];
                    T = T * 256 + acc[1][tf][r];
                    T = T * 256 + acc[0][tf][r];
                    cs[p & 1][tw2 * 32 + tf * 16 + lq * 4 + r][mw * 16 + lm] =
                        (float)((double)T * INV231 + bv);
                }
        }
        if (wave == 8 && p >= 1) {
            const int pq = p - 1, buf = pq & 1;
            float cvA[32], cvB[32];
#pragma unroll
            for (int j = 0; j < 32; ++j) cvA[j] = cs[buf][j][lane];
#pragma unroll
            for (int j = 0; j < 32; ++j) cvB[j] = cs[buf][32 + j][lane];
            {   // t-word pq*2
                unsigned mword = 0;
#pragma unroll
                for (int j = 0; j < 32; ++j) {
                    double c = (double)cvA[j];
                    double a = 0.95 * u + c;
                    u = sprev ? c : a;
                    bool s = (u >= 1.0);
                    mword |= (s ? 1u : 0u) << j;
                    sprev = s;
                }
                mask_ws[((long)b * 32 + pq * 2 + 0) * 2048 + m0 + lane] = mword;
            }
            {   // t-word pq*2+1
                unsigned mword = 0;
#pragma unroll
                for (int j = 0; j < 32; ++j) {
                    double c = (double)cvB[j];
                    double a = 0.95 * u + c;
                    u = sprev ? c : a;
                    bool s = (u >= 1.0);
                    mword |= (s ? 1u : 0u) << j;
                    sprev = s;
                }
                mask_ws[((long)b * 32 + pq * 2 + 1) * 2048 + m0 + lane] = mword;
            }
        }
        asm volatile("s_waitcnt lgkmcnt(0)" ::: "memory");
        __builtin_amdgcn_s_barrier();
        __builtin_amdgcn_sched_barrier(0);
    }
}

// ======================= combined mask expander =======================
// masks [b][32][2048] -> spk8 i8 [b][32 kt][1024 t][64 m]  AND
//                        spk1 f32 [b][2048 m][1024 t]
__global__ __launch_bounds__(256) void expand_both(
    const unsigned* __restrict__ mask_ws,
    unsigned char* __restrict__ spk8,
    float* __restrict__ spk1)
{
    __shared__ unsigned msk[64][33];
    const int b = blockIdx.x, kt = blockIdx.y;
    const int tid = threadIdx.x;
#pragma unroll
    for (int i = 0; i < 8; ++i) {
        int idx = tid + i * 256;            // 0..2047
        int tw = idx >> 6, m = idx & 63;
        msk[m][tw] = mask_ws[((long)b * 32 + tw) * 2048 + kt * 64 + m];
    }
    __syncthreads();
    unsigned char* dst = spk8 + ((long)b * 32 + kt) * 1024 * 64;
#pragma unroll
    for (int i = 0; i < 16; ++i) {
        int off = tid + i * 256;            // 16-B chunk index 0..4095
        int t = off >> 2, mq = off & 3;
        int tw = t >> 5, sh = t & 31;
        unsigned w0 = 0, w1 = 0, w2 = 0, w3 = 0;
#pragma unroll
        for (int j = 0; j < 4; ++j) {
            w0 |= ((msk[mq * 16 + j][tw] >> sh) & 1u) << (8 * j);
            w1 |= ((msk[mq * 16 + 4 + j][tw] >> sh) & 1u) << (8 * j);
            w2 |= ((msk[mq * 16 + 8 + j][tw] >> sh) & 1u) << (8 * j);
            w3 |= ((msk[mq * 16 + 12 + j][tw] >> sh) & 1u) << (8 * j);
        }
        *(uint4*)&dst[(long)off * 16] = (uint4){w0, w1, w2, w3};
    }
    const int rr = tid >> 5, l5 = tid & 31;
    const int sh1 = (l5 & 7) * 4;
#pragma unroll
    for (int rep = 0; rep < 8; ++rep) {
        const int row = rr + rep * 8;       // 0..63
        float* d1 = spk1 + ((long)b * 2048 + kt * 64 + row) * 1024;
#pragma unroll
        for (int j = 0; j < 8; j++) {
            const int t = l5 * 4 + j * 128;
            const unsigned w = msk[row][(l5 >> 3) + j * 4];
            float4 o;
            o.x = ((w >> sh1) & 1u) ? 1.f : 0.f;
            o.y = ((w >> (sh1 + 1)) & 1u) ? 1.f : 0.f;
            o.z = ((w >> (sh1 + 2)) & 1u) ? 1.f : 0.f;
            o.w = ((w >> (sh1 + 3)) & 1u) ? 1.f : 0.f;
            *(float4*)&d1[t] = o;
        }
    }
}

// ======================= fused layer-2 GEMM + LIF =======================
// Block = (b, 16 m) x ALL 1024 t. 576 threads: waves 0-7 GEMM (16t x 16m
// each per 128-t pass; 2+ waves/SIMD -- the r11-proven occupancy lever),
// wave 8 = LIF2 (lanes 0-15, chain for row m0+lane, writes spk2 directly).
// LDS: Ws[32][4][16][64] = 128 KB (whole K=2048 slab, staged once ->
// barrier-free k-loop) + cs[2][128][17] = 17.4 KB.
// 8 t-passes of 128; raw lgkmcnt-only pass barriers; act ring dist 2.
// Grid dim3(32 b, 16 mb): same-b blocks share one XCD's L2 for spk8.
__global__ __launch_bounds__(576, 1) void gemm_lif2(
    const signed char* __restrict__ wp,     // [32][4][256][64] swizzled
    const unsigned char* __restrict__ act,  // [b][32][1024][64] spk8
    const float* __restrict__ bias,         // (256)
    float* __restrict__ spk2)               // [b][256][1024] f32 spikes
{
    __shared__ signed char Ws[32][4][16][64];  // 128 KB
    __shared__ float cs[2][128][17];           // 17.4 KB

    const int b = blockIdx.x, m0 = blockIdx.y * 16;
    const int tid = threadIdx.x, lane = tid & 63, wave = tid >> 6;
    const int lm = lane & 15, lq = lane >> 4;
    const int fro = ((lq ^ (lm >> 1)) & 3) * 16;   // swizzled LDS read offset
    const unsigned char* ab = act + (long)b * 32 * 1024 * 64;

    i32x4 areg[4];      // 4-slot ring, 1 t-frag, prefetch distance 2
    double bvr[4] = {0.0, 0.0, 0.0, 0.0};

    if (wave < 8) {
        // stage whole weight slab: 128 slabs (kt,pl) of [16][64]=1KB each,
        // exactly one GLDS (64 lanes x 16 B) per slab; 16 slabs/wave
        const int gl_row = lane >> 2, gl_col = (lane & 3) * 16;
#pragma unroll
        for (int j = 0; j < 16; ++j) {
            const int r = wave + 8 * j;          // slab id 0..127
            const int kt = r >> 2, pl = r & 3;
            const signed char* g =
                wp + (((long)kt * 4 + pl) * 256 + m0 + gl_row) * 64 + gl_col;
            GLDS(g, &Ws[kt][pl][0][0]);
        }
#pragma unroll
        for (int r = 0; r < 4; ++r)
            bvr[r] = (double)bias[m0 + lq * 4 + r];
        // act ring prologue: kt 0 (slot 0), kt 1 (slot 1), pass-0 t-slice
        {
            const long wt0 = wave * 16 + lm;
            areg[0] = *(const i32x4*)&ab[wt0 * 64 + lq * 16];
            areg[1] = *(const i32x4*)&ab[((long)1 * 1024 + wt0) * 64 + lq * 16];
        }
    }
    __syncthreads();   // full drain: GLDS weights must be resident

    // LIF2 state (wave 8, lanes 0-15: chain for row m0+lane)
    double u = 0.0;
    bool sprev = false;
    float* sp2 = spk2 + ((long)b * 256 + m0 + (lane & 15)) * 1024;

    for (int p = 0; p < 9; ++p) {
        if (wave < 8 && p < 8) {
            i32x4 acc[4];   // [plane]
#pragma unroll
            for (int pp = 0; pp < 4; pp++) acc[pp] = (i32x4)0;

            // barrier-free k-loop over all 32 k-tiles (weights resident)
#pragma unroll 4
            for (int kt = 0; kt < 32; ++kt) {
                {
                    int vn = p * 32 + kt + 2;          // virtual act iter
                    if (vn > 255) vn = 255;            // redundant reload
                    const int pn = vn >> 5, kn = vn & 31;
                    const long tt = (long)pn * 128 + wave * 16 + lm;
                    areg[(kt + 2) & 3] = *(const i32x4*)
                        &ab[((long)kn * 1024 + tt) * 64 + lq * 16];
                }
                __builtin_amdgcn_s_setprio(1);
#pragma unroll
                for (int pl = 0; pl < 4; pl++) {
                    i32x4 w0 = *(const i32x4*)&Ws[kt][pl][lm][fro];
                    acc[pl] = __builtin_amdgcn_mfma_i32_16x16x64_i8(
                        w0, areg[kt & 3], acc[pl], 0, 0, 0);
                }
                __builtin_amdgcn_s_setprio(0);
            }
            // Horner -> exact f32 current -> cs[p&1][t][m]
            // D[m][t]: row m = lq*4+r, col t = wave*16 + lm
#pragma unroll
            for (int r = 0; r < 4; r++) {
                long T = acc[3][r];
                T = T * 256 + acc[2][r];
                T = T * 256 + acc[1][r];
                T = T * 256 + acc[0][r];
                cs[p & 1][wave * 16 + lm][lq * 4 + r] =
                    (float)((double)T * INV231 + bvr[r]);
            }
        }
        if (wave == 8 && p >= 1 && lane < 16) {
            const int pq = p - 1, buf = pq & 1;
            float* sp = sp2 + pq * 128;
            // 4 groups of 32 steps, register-preload pipelined (r5 proven),
            // spikes stored f32 directly (independent stores, no waits)
            float cvA[32], cvB[32];
#pragma unroll
            for (int j = 0; j < 32; ++j) cvA[j] = cs[buf][j][lane];
#pragma unroll
            for (int j = 0; j < 32; ++j) cvB[j] = cs[buf][32 + j][lane];
            {   // g = 0 (chain cvA)
#pragma unroll
                for (int j = 0; j < 32; ++j) {
                    double c = (double)cvA[j];
                    double a = 0.95 * u + c;
                    u = sprev ? c : a;
                    bool s = (u >= 1.0);
                    sp[j] = s ? 1.f : 0.f;
                    sprev = s;
                }
            }
#pragma unroll
            for (int j = 0; j < 32; ++j) cvA[j] = cs[buf][64 + j][lane];
            {   // g = 1 (chain cvB)
#pragma unroll
                for (int j = 0; j < 32; ++j) {
                    double c = (double)cvB[j];
                    double a = 0.95 * u + c;
                    u = sprev ? c : a;
                    bool s = (u >= 1.0);
                    sp[32 + j] = s ? 1.f : 0.f;
                    sprev = s;
                }
            }
#pragma unroll
            for (int j = 0; j < 32; ++j) cvB[j] = cs[buf][96 + j][lane];
            {   // g = 2 (chain cvA)
#pragma unroll
                for (int j = 0; j < 32; ++j) {
                    double c = (double)cvA[j];
                    double a = 0.95 * u + c;
                    u = sprev ? c : a;
                    bool s = (u >= 1.0);
                    sp[64 + j] = s ? 1.f : 0.f;
                    sprev = s;
                }
            }
            {   // g = 3 (chain cvB)
#pragma unroll
                for (int j = 0; j < 32; ++j) {
                    double c = (double)cvB[j];
                    double a = 0.95 * u + c;
                    u = sprev ? c : a;
                    bool s = (u >= 1.0);
                    sp[96 + j] = s ? 1.f : 0.f;
                    sprev = s;
                }
            }
        }
        // raw pass barrier: only LDS (cs) crosses it -> lgkmcnt(0) suffices;
        // in-flight GLOBAL act loads / spike stores intentionally survive.
        asm volatile("s_waitcnt lgkmcnt(0)" ::: "memory");
        __builtin_amdgcn_s_barrier();
        __builtin_amdgcn_sched_barrier(0);
    }
}

// ======================= fallback (round 3, proven) =======================

__device__ inline void split3(float w, _Float16& q0, _Float16& q1, _Float16& q2) {
    float p0 = rintf(w * 4096.f) * 2.44140625e-4f;
    float r1 = w - p0;
    float p1s = rintf(r1 * 8388608.f) * 2.44140625e-4f;
    float r2 = r1 - p1s * 4.8828125e-4f;
    float p2s = rintf(r2 * 1.7179869184e10f) * 1.220703125e-4f;
    q0 = (_Float16)p0; q1 = (_Float16)p1s; q2 = (_Float16)p2s;
}

__global__ __launch_bounds__(256) void gemm_f16x3_kernel(
    const float* __restrict__ A, const float* __restrict__ Bmat,
    const float* __restrict__ bias, float* __restrict__ C,
    int M, int N, int K, long sB, long sC)
{
    __shared__ _Float16 As[3][128][40];
    __shared__ _Float16 Bsh[128][40];
    const int batch = blockIdx.z;
    const float* Bp = Bmat + (long)batch * sB;
    float* Cp = C + (long)batch * sC;
    const int m0 = blockIdx.y * 128, n0 = blockIdx.x * 128;
    const int tid = threadIdx.x, lane = tid & 63, wave = tid >> 6;
    const int wrow = (wave >> 1) * 64, wcol = (wave & 1) * 64;
    const int lm = lane & 15, lq = lane >> 4;
    const int a_mo = tid >> 3, a_kc = (tid & 7) * 4;
    const int b_kq = tid >> 5, b_nq = tid & 31;

    f32x4 acc[3][4][4];
#pragma unroll
    for (int p = 0; p < 3; p++)
#pragma unroll
        for (int i = 0; i < 4; i++)
#pragma unroll
            for (int j = 0; j < 4; j++) acc[p][i][j] = (f32x4)0.f;

    for (int k0 = 0; k0 < K; k0 += 32) {
#pragma unroll
        for (int i = 0; i < 4; i++) {
            const int m = i * 32 + a_mo;
            float4 w = *(const float4*)&A[(long)(m0 + m) * K + k0 + a_kc];
            _Float16 a0[4], a1[4], a2[4];
            split3(w.x, a0[0], a1[0], a2[0]);
            split3(w.y, a0[1], a1[1], a2[1]);
            split3(w.z, a0[2], a1[2], a2[2]);
            split3(w.w, a0[3], a1[3], a2[3]);
            *(f16x4*)&As[0][m][a_kc] = (f16x4){a0[0], a0[1], a0[2], a0[3]};
            *(f16x4*)&As[1][m][a_kc] = (f16x4){a1[0], a1[1], a1[2], a1[3]};
            *(f16x4*)&As[2][m][a_kc] = (f16x4){a2[0], a2[1], a2[2], a2[3]};
        }
        {
            float4 r0 = *(const float4*)&Bp[(long)(k0 + b_kq * 4 + 0) * N + n0 + b_nq * 4];
            float4 r1 = *(const float4*)&Bp[(long)(k0 + b_kq * 4 + 1) * N + n0 + b_nq * 4];
            float4 r2 = *(const float4*)&Bp[(long)(k0 + b_kq * 4 + 2) * N + n0 + b_nq * 4];
            float4 r3 = *(const float4*)&Bp[(long)(k0 + b_kq * 4 + 3) * N + n0 + b_nq * 4];
            *(f16x4*)&Bsh[b_nq * 4 + 0][b_kq * 4] =
                (f16x4){(_Float16)r0.x, (_Float16)r1.x, (_Float16)r2.x, (_Float16)r3.x};
            *(f16x4*)&Bsh[b_nq * 4 + 1][b_kq * 4] =
                (f16x4){(_Float16)r0.y, (_Float16)r1.y, (_Float16)r2.y, (_Float16)r3.y};
            *(f16x4*)&Bsh[b_nq * 4 + 2][b_kq * 4] =
                (f16x4){(_Float16)r0.z, (_Float16)r1.z, (_Float16)r2.z, (_Float16)r3.z};
            *(f16x4*)&Bsh[b_nq * 4 + 3][b_kq * 4] =
                (f16x4){(_Float16)r0.w, (_Float16)r1.w, (_Float16)r2.w, (_Float16)r3.w};
        }
        __syncthreads();
        f16x8 bf[4];
#pragma unroll
        for (int j = 0; j < 4; j++)
            bf[j] = *(const f16x8*)&Bsh[wcol + j * 16 + lm][lq * 8];
#pragma unroll
        for (int p = 0; p < 3; p++) {
            f16x8 af[4];
#pragma unroll
            for (int i = 0; i < 4; i++)
                af[i] = *(const f16x8*)&As[p][wrow + i * 16 + lm][lq * 8];
#pragma unroll
            for (int i = 0; i < 4; i++)
#pragma unroll
                for (int j = 0; j < 4; j++)
                    acc[p][i][j] = __builtin_amdgcn_mfma_f32_16x16x32_f16(
                        af[i], bf[j], acc[p][i][j], 0, 0, 0);
        }
        __syncthreads();
    }
#pragma unroll
    for (int i = 0; i < 4; i++)
#pragma unroll
        for (int r = 0; r < 4; r++) {
            const int row = m0 + wrow + i * 16 + lq * 4 + r;
            const double bv = (double)bias[row];
#pragma unroll
            for (int j = 0; j < 4; j++) {
                double s = (double)acc[0][i][j][r]
                         + (double)acc[1][i][j][r] * 4.8828125e-4
                         + (double)acc[2][i][j][r] * 4.76837158203125e-7 + bv;
                Cp[(long)row * N + n0 + wcol + j * 16 + lm] = (float)s;
            }
        }
}

__global__ __launch_bounds__(256) void lif_rows(float* __restrict__ data,
                                                long nrows, int T)
{
    long r = (long)blockIdx.x * blockDim.x + threadIdx.x;
    if (r >= nrows) return;
    float* p = data + r * (long)T;
    double v = 0.0;
    for (int t = 0; t < T; t += 4) {
        float4 c = *(float4*)(p + t);
        float4 s;
        v = 0.95 * v + (double)c.x; s.x = (v >= 1.0) ? 1.f : 0.f; if (v >= 1.0) v = 0.0;
        v = 0.95 * v + (double)c.y; s.y = (v >= 1.0) ? 1.f : 0.f; if (v >= 1.0) v = 0.0;
        v = 0.95 * v + (double)c.z; s.z = (v >= 1.0) ? 1.f : 0.f; if (v >= 1.0) v = 0.0;
        v = 0.95 * v + (double)c.w; s.w = (v >= 1.0) ? 1.f : 0.f; if (v >= 1.0) v = 0.0;
        *(float4*)(p + t) = s;
    }
}

// ======================= launch =======================

extern "C" void kernel_launch(void* const* d_in, const int* in_sizes, int n_in,
                              void* d_out, int out_size, void* d_ws, size_t ws_size,
                              hipStream_t stream)
{
    const float* x  = (const float*)d_in[0];  // (32, 512, 1024)
    const float* w1 = (const float*)d_in[1];  // (2048, 512)
    const float* b1 = (const float*)d_in[2];  // (2048)
    const float* w2 = (const float*)d_in[3];  // (256, 2048)
    const float* b2 = (const float*)d_in[4];  // (256)

    float* out  = (float*)d_out;
    float* spk1 = out;                              // (32, 2048, 1024)
    float* spk2 = out + (long)32 * 2048 * 1024;     // (32, 256, 1024)

    const size_t WP1 = 4194304;        // [8][4][2048][64] i8
    const size_t WP2 = 2097152;        // [32][4][256][64] i8
    const size_t X8T = 16777216;       // [32][8][1024][64] i8
    const size_t SPK = 67108864;       // [32][32][1024][64] i8
    const size_t MSK = 8388608;        // [32][32][2048] u32
    const size_t NEED = WP1 + WP2 + X8T + SPK + MSK;

    if (ws_size >= NEED) {
        char* ws = (char*)d_ws;
        signed char* wp1 = (signed char*)ws;
        signed char* wp2 = (signed char*)(ws + WP1);
        unsigned char* x8t = (unsigned char*)(ws + WP1 + WP2);
        unsigned char* spk8 = (unsigned char*)(ws + WP1 + WP2 + X8T);
        unsigned* mask_ws = (unsigned*)(ws + WP1 + WP2 + X8T + SPK);

        prep_w8_both<<<1536, 256, 0, stream>>>(w1, wp1, w2, wp2);
        prep_x8<<<dim3(16, 8, 32), 256, 0, stream>>>(x, x8t);

        // layer 1: fused GEMM+LIF -> masks only; 8 GEMM waves + 1 LIF wave
        gemm_lif1<<<dim3(32, 32), 576, 0, stream>>>(wp1, x8t, b1, mask_ws);

        // combined expansion: masks -> spk8 i8 + spk1 f32 (one kernel)
        expand_both<<<dim3(32, 32), 256, 0, stream>>>(mask_ws, spk8, spk1);

        // layer 2: fused GEMM+LIF -> spk2 f32 directly; 8 GEMM + 1 LIF wave
        gemm_lif2<<<dim3(32, 16), 576, 0, stream>>>(wp2, spk8, b2, spk2);
    } else {
        gemm_f16x3_kernel<<<dim3(8, 16, 32), 256, 0, stream>>>(
            w1, x, b1, spk1, 2048, 1024, 512, (long)512 * 1024, (long)2048 * 1024);
        lif_rows<<<(65536 + 255) / 256, 256, 0, stream>>>(spk1, 65536, 1024);
        gemm_f16x3_kernel<<<dim3(8, 2, 32), 256, 0, stream>>>(
            w2, spk1, b2, spk2, 256, 1024, 2048, (long)2048 * 1024, (long)256 * 1024);
        lif_rows<<<(8192 + 255) / 256, 256, 0, stream>>>(spk2, 8192, 1024);
    }
}